// Round 10
// baseline (27.798 us; speedup 1.0000x reference)
//
#include <hip/hip_runtime.h>

#define N       2304       // T*H*W = 4*24*24
#define CIN     64
#define CHALF   32
#define KT      17         // Taylor powers 0..16
#define T1      64         // K1 tile (positions)
#define NB1     (N / T1)   // 36
#define T2      16         // K2 tile
#define NB2     (N / T2)   // 144
#define NCOEF   1088       // den[17][32] @0, num[17][32] @544
#define CSTRIDE 44         // cfl row stride: den @0..16, num @20..36

__device__ __constant__ float INVF_C[KT] = {
    1.0f, 1.0f, 0.5f, 1.6666667e-1f, 4.1666668e-2f, 8.3333333e-3f,
    1.3888889e-3f, 1.9841270e-4f, 2.4801587e-5f, 2.7557319e-6f,
    2.7557319e-7f, 2.5052108e-8f, 2.0876756e-9f, 1.6059044e-10f,
    1.1470746e-11f, 7.6471637e-13f, 4.7794773e-14f };

// ---------------------------------------------------------------------------
// K1: 36 blocks x 512. Wave w: theta/phi/g projections for channel-quad w
// (x column in VGPRs, weights via wave-uniform s_loads). theta -> v1 global;
// phi/g -> LDS. Then Taylor-moment phase (c, k-quad q, pos-group pg) with
// b128 LDS reads, 2-level LDS reduce -> partial[blk][1088] (raw power sums).
// ---------------------------------------------------------------------------
__global__ __launch_bounds__(512) void k_projmom(
    const float* __restrict__ x,
    const float* __restrict__ tw, const float* __restrict__ tb,
    const float* __restrict__ pw, const float* __restrict__ pb,
    const float* __restrict__ gw, const float* __restrict__ gb,
    float* __restrict__ v1, float* __restrict__ partial)
{
    __shared__ float bl[CHALF][68];      // phi values, padded rows (4-way max)
    __shared__ float gl[CHALF][68];      // g values
    __shared__ float red[4][8][4][32];   // [q][j][pg][c]  16 KB, c-contiguous
    __shared__ float redg[4][32];        // [pg][c]  sum of g

    const int tid  = threadIdx.x;
    const int lane = tid & 63;
    const int w    = tid >> 6;           // 0..7 (wave id, uniform)
    const int n0   = blockIdx.x * T1;

    // x column (this tile, this position) in registers; L1-shared across waves
    float xr[CIN];
    #pragma unroll
    for (int c = 0; c < CIN; ++c)
        xr[c] = x[c * N + n0 + lane];

    // ---- three projections for channel-quad co0 = 4w -----------------------
    {
        const int co0 = w * 4;
        float a[4];

        const float* wr = tw + co0 * CIN;          // wave-uniform -> s_load
        a[0] = a[1] = a[2] = a[3] = 0.f;
        #pragma unroll
        for (int c = 0; c < CIN; ++c) {
            a[0] = fmaf(wr[c],           xr[c], a[0]);
            a[1] = fmaf(wr[CIN + c],     xr[c], a[1]);
            a[2] = fmaf(wr[2 * CIN + c], xr[c], a[2]);
            a[3] = fmaf(wr[3 * CIN + c], xr[c], a[3]);
        }
        #pragma unroll
        for (int i = 0; i < 4; ++i)
            v1[(co0 + i) * N + n0 + lane] = a[i] + tb[co0 + i];

        wr = pw + co0 * CIN;
        a[0] = a[1] = a[2] = a[3] = 0.f;
        #pragma unroll
        for (int c = 0; c < CIN; ++c) {
            a[0] = fmaf(wr[c],           xr[c], a[0]);
            a[1] = fmaf(wr[CIN + c],     xr[c], a[1]);
            a[2] = fmaf(wr[2 * CIN + c], xr[c], a[2]);
            a[3] = fmaf(wr[3 * CIN + c], xr[c], a[3]);
        }
        #pragma unroll
        for (int i = 0; i < 4; ++i)
            bl[co0 + i][lane] = a[i] + pb[co0 + i];

        wr = gw + co0 * CIN;
        a[0] = a[1] = a[2] = a[3] = 0.f;
        #pragma unroll
        for (int c = 0; c < CIN; ++c) {
            a[0] = fmaf(wr[c],           xr[c], a[0]);
            a[1] = fmaf(wr[CIN + c],     xr[c], a[1]);
            a[2] = fmaf(wr[2 * CIN + c], xr[c], a[2]);
            a[3] = fmaf(wr[3 * CIN + c], xr[c], a[3]);
        }
        #pragma unroll
        for (int i = 0; i < 4; ++i)
            gl[co0 + i][lane] = a[i] + gb[co0 + i];
    }
    __syncthreads();

    // ---- moments: thread = (c, q, pg); k in {4q+1..4q+4}, 16 positions -----
    {
        const int c  = tid & 31;
        const int q  = (tid >> 5) & 3;
        const int pg = tid >> 7;
        float d[4]  = {0.f, 0.f, 0.f, 0.f};
        float nm[4] = {0.f, 0.f, 0.f, 0.f};
        float sg    = 0.f;
        #pragma unroll
        for (int jj = 0; jj < 4; ++jj) {
            float4 b4 = *(const float4*)&bl[c][pg * 16 + jj * 4];
            float4 g4 = *(const float4*)&gl[c][pg * 16 + jj * 4];
            #pragma unroll
            for (int e = 0; e < 4; ++e) {
                float bb = (e==0) ? b4.x : (e==1) ? b4.y : (e==2) ? b4.z : b4.w;
                float gg = (e==0) ? g4.x : (e==1) ? g4.y : (e==2) ? g4.z : g4.w;
                float b2 = bb * bb, b4v = b2 * b2;
                float p0 = (q == 0) ? 1.0f
                         : (q == 1) ? b4v
                         : (q == 2) ? b4v * b4v
                                    : (b4v * b4v) * b4v;   // b^{4q}
                float p1 = p0 * bb, p2 = p1 * bb, p3 = p2 * bb, p4 = p3 * bb;
                d[0] += p1; nm[0] = fmaf(p1, gg, nm[0]);
                d[1] += p2; nm[1] = fmaf(p2, gg, nm[1]);
                d[2] += p3; nm[2] = fmaf(p3, gg, nm[2]);
                d[3] += p4; nm[3] = fmaf(p4, gg, nm[3]);
                sg += gg;
            }
        }
        #pragma unroll
        for (int i = 0; i < 4; ++i) {
            red[q][i][pg][c]     = d[i];
            red[q][4 + i][pg][c] = nm[i];
        }
        if (q == 0) redg[pg][c] = sg;
    }
    __syncthreads();

    // ---- write partial[blk][1088]: coalesced, conflict-free LDS reads ------
    {
        float* pp = partial + blockIdx.x * NCOEF;
        #pragma unroll
        for (int e = tid; e < 1024; e += 512) {
            int c  = e & 31;
            int kk = (e >> 5) & 15;          // k = kk+1 in 1..16
            int dn = e >> 9;                 // 0 = den, 1 = num
            int q  = kk >> 2, j = (kk & 3) + 4 * dn;
            float s = red[q][j][0][c] + red[q][j][1][c]
                    + red[q][j][2][c] + red[q][j][3][c];
            pp[dn * 544 + (kk + 1) * 32 + c] = s;
        }
        if (tid < 32)
            pp[544 + tid] = redg[0][tid] + redg[1][tid]
                          + redg[2][tid] + redg[3][tid];   // k=0 num: sum g
        else if (tid < 64)
            pp[tid - 32] = (float)T1;                      // k=0 den: sum b^0
    }
}

// ---------------------------------------------------------------------------
// K2: 144 blocks x 256. Reduce partial[36][1088] -> cfl[c][44] (1/k! folded,
// transposed for b128 Horner loads); Horner y = num(a)/den(a) in-register
// from v1; out-projection + residual.
// ---------------------------------------------------------------------------
__global__ __launch_bounds__(256) void k_eval(
    const float* __restrict__ x,
    const float* __restrict__ kw, const float* __restrict__ kb,
    const float* __restrict__ v1, const float* __restrict__ partial,
    float* __restrict__ out)
{
    __shared__ float kwt[CHALF][68];            // [c][co]
    __shared__ __align__(16) float cfl[CHALF][CSTRIDE];
    __shared__ float ys[T2][36];                // [pos][c]
    __shared__ float kbs[CIN];

    const int tid = threadIdx.x;
    const int n0  = blockIdx.x * T2;

    for (int idx = tid; idx < CIN * CHALF; idx += 256) {
        int co = idx >> 5, c = idx & 31;
        kwt[c][co] = kw[idx];                   // kw row-major [co=64][c=32]
    }
    if (tid < CIN) kbs[tid] = kb[tid];

    // ---- reduce 36 partial rows (deterministic order), fold 1/k! -----------
    for (int col = tid; col < NCOEF / 4; col += 256) {
        float4 v = make_float4(0.f, 0.f, 0.f, 0.f);
        #pragma unroll 6
        for (int s = 0; s < NB1; ++s) {
            float4 p = *(const float4*)&partial[s * NCOEF + col * 4];
            v.x += p.x; v.y += p.y; v.z += p.z; v.w += p.w;
        }
        #pragma unroll
        for (int i = 0; i < 4; ++i) {
            int   e  = col * 4 + i;
            int   dn = (e >= 544) ? 1 : 0;
            int   k  = (e - dn * 544) >> 5;
            int   c  = e & 31;
            float vv = (i==0) ? v.x : (i==1) ? v.y : (i==2) ? v.z : v.w;
            cfl[c][dn * 20 + k] = vv * INVF_C[k];
        }
    }
    __syncthreads();

    // ---- Horner: thread = (c = tid>>3, pp = tid&7), 2 positions ------------
    {
        const int c  = tid >> 3;
        const int pp = tid & 7;
        float dc[20], nc[20];
        #pragma unroll
        for (int qq = 0; qq < 5; ++qq) {
            *(float4*)&dc[qq * 4] = *(const float4*)&cfl[c][qq * 4];
            *(float4*)&nc[qq * 4] = *(const float4*)&cfl[c][20 + qq * 4];
        }
        float2 a2 = *(const float2*)&v1[c * N + n0 + pp * 2];
        #pragma unroll
        for (int e = 0; e < 2; ++e) {
            float a   = e ? a2.y : a2.x;
            float den = dc[KT - 1], num = nc[KT - 1];
            #pragma unroll
            for (int k = KT - 2; k >= 0; --k) {
                den = fmaf(den, a, dc[k]);
                num = fmaf(num, a, nc[k]);
            }
            ys[pp * 2 + e][c] = num / den;
        }
    }
    __syncthreads();

    // ---- out-projection + residual: thread = (pos = tid&15, coq = tid>>4) --
    {
        const int pos = tid & 15;
        const int coq = tid >> 4;               // 0..15 -> co = coq*4 + i
        float yv[CHALF];
        #pragma unroll
        for (int qq = 0; qq < 8; ++qq)
            *(float4*)&yv[qq * 4] = *(const float4*)&ys[pos][qq * 4];

        float acc[4] = {0.f, 0.f, 0.f, 0.f};
        #pragma unroll
        for (int c = 0; c < CHALF; ++c) {
            float4 wv = *(const float4*)&kwt[c][coq * 4];
            acc[0] = fmaf(wv.x, yv[c], acc[0]);
            acc[1] = fmaf(wv.y, yv[c], acc[1]);
            acc[2] = fmaf(wv.z, yv[c], acc[2]);
            acc[3] = fmaf(wv.w, yv[c], acc[3]);
        }
        #pragma unroll
        for (int i = 0; i < 4; ++i) {
            int off = (coq * 4 + i) * N + n0 + pos;
            out[off] = x[off] + acc[i] + kbs[coq * 4 + i];
        }
    }
}

// ---------------------------------------------------------------------------
extern "C" void kernel_launch(void* const* d_in, const int* in_sizes, int n_in,
                              void* d_out, int out_size, void* d_ws, size_t ws_size,
                              hipStream_t stream)
{
    const float* x  = (const float*)d_in[0];
    const float* tw = (const float*)d_in[1];
    const float* tb = (const float*)d_in[2];
    const float* pw = (const float*)d_in[3];
    const float* pb = (const float*)d_in[4];
    const float* gw = (const float*)d_in[5];
    const float* gb = (const float*)d_in[6];
    const float* kw = (const float*)d_in[7];
    const float* kb = (const float*)d_in[8];
    float* out = (float*)d_out;

    // workspace (floats): v1 @0 (73728), partial[36][1088] @73728
    float* ws      = (float*)d_ws;
    float* v1      = ws;
    float* partial = ws + 73728;

    k_projmom<<<dim3(NB1), dim3(512), 0, stream>>>(
        x, tw, tb, pw, pb, gw, gb, v1, partial);

    k_eval<<<dim3(NB2), dim3(256), 0, stream>>>(
        x, kw, kb, v1, partial, out);
}

// Round 11
// 20.282 us; speedup vs baseline: 1.3706x; 1.3706x over previous
//
#include <hip/hip_runtime.h>

#define N       2304       // T*H*W = 4*24*24
#define CIN     64
#define CHALF   32
#define KT      17         // Taylor powers 0..16
#define T1      64         // K1 tile (positions)
#define NB1     (N / T1)   // 36
#define T2      16         // K2 tile
#define NB2     (N / T2)   // 144
#define NCOEF   1088       // den[17][32] @0, num[17][32] @544
#define CSTRIDE 44         // cfl row stride: den @0..16, num @20..36

__device__ __constant__ float INVF_C[KT] = {
    1.0f, 1.0f, 0.5f, 1.6666667e-1f, 4.1666668e-2f, 8.3333333e-3f,
    1.3888889e-3f, 1.9841270e-4f, 2.4801587e-5f, 2.7557319e-6f,
    2.7557319e-7f, 2.5052108e-8f, 2.0876756e-9f, 1.6059044e-10f,
    1.1470746e-11f, 7.6471637e-13f, 4.7794773e-14f };

// ---------------------------------------------------------------------------
// K1: grid (36 tiles, 8 channel-quads), block = 1 wave (64 threads).
// Lane = position. x column in VGPRs (coalesced); theta/phi/g for 4 channels
// via wave-uniform s_load weight rows. theta -> v1. phi/g -> registers ->
// [4][66] LDS transpose -> per-(channel, 16-lane group) Taylor powers ->
// intra-group butterfly -> partial[tile][1088] raw power sums.
// ---------------------------------------------------------------------------
__global__ __launch_bounds__(64) void k_pm(
    const float* __restrict__ x,
    const float* __restrict__ tw, const float* __restrict__ tb,
    const float* __restrict__ pw, const float* __restrict__ pb,
    const float* __restrict__ gw, const float* __restrict__ gb,
    float* __restrict__ v1, float* __restrict__ partial)
{
    __shared__ float bl[4][66];
    __shared__ float gl[4][66];

    const int lane = threadIdx.x;
    const int n0   = blockIdx.x * T1;
    const int cg0  = blockIdx.y * 4;       // first of this block's 4 channels

    float xr[CIN];
    #pragma unroll
    for (int c = 0; c < CIN; ++c)
        xr[c] = x[c * N + n0 + lane];      // coalesced 256B per load

    // ---- theta -> v1 -------------------------------------------------------
    {
        const float* wr = tw + cg0 * CIN;  // wave-uniform -> s_load
        float a[4] = {0.f, 0.f, 0.f, 0.f};
        #pragma unroll
        for (int c = 0; c < CIN; ++c) {
            a[0] = fmaf(wr[c],           xr[c], a[0]);
            a[1] = fmaf(wr[CIN + c],     xr[c], a[1]);
            a[2] = fmaf(wr[2 * CIN + c], xr[c], a[2]);
            a[3] = fmaf(wr[3 * CIN + c], xr[c], a[3]);
        }
        #pragma unroll
        for (int i = 0; i < 4; ++i)
            v1[(cg0 + i) * N + n0 + lane] = a[i] + tb[cg0 + i];
    }

    // ---- phi, g -> registers -> LDS ----------------------------------------
    {
        const float* wr = pw + cg0 * CIN;
        float a[4] = {0.f, 0.f, 0.f, 0.f};
        #pragma unroll
        for (int c = 0; c < CIN; ++c) {
            a[0] = fmaf(wr[c],           xr[c], a[0]);
            a[1] = fmaf(wr[CIN + c],     xr[c], a[1]);
            a[2] = fmaf(wr[2 * CIN + c], xr[c], a[2]);
            a[3] = fmaf(wr[3 * CIN + c], xr[c], a[3]);
        }
        #pragma unroll
        for (int i = 0; i < 4; ++i)
            bl[i][lane] = a[i] + pb[cg0 + i];
    }
    {
        const float* wr = gw + cg0 * CIN;
        float a[4] = {0.f, 0.f, 0.f, 0.f};
        #pragma unroll
        for (int c = 0; c < CIN; ++c) {
            a[0] = fmaf(wr[c],           xr[c], a[0]);
            a[1] = fmaf(wr[CIN + c],     xr[c], a[1]);
            a[2] = fmaf(wr[2 * CIN + c], xr[c], a[2]);
            a[3] = fmaf(wr[3 * CIN + c], xr[c], a[3]);
        }
        #pragma unroll
        for (int i = 0; i < 4; ++i)
            gl[i][lane] = a[i] + gb[cg0 + i];
    }
    __syncthreads();

    // ---- moments: group = channel (lane>>4), 4 positions per lane ----------
    {
        const int c = lane >> 4;
        const int l = lane & 15;

        float den[KT], num[KT];
        #pragma unroll
        for (int k = 0; k < KT; ++k) { den[k] = 0.f; num[k] = 0.f; }

        float4 bq = *(const float4*)&bl[c][4 * l];
        float4 gq = *(const float4*)&gl[c][4 * l];
        #pragma unroll
        for (int e = 0; e < 4; ++e) {
            float b = (e==0) ? bq.x : (e==1) ? bq.y : (e==2) ? bq.z : bq.w;
            float g = (e==0) ? gq.x : (e==1) ? gq.y : (e==2) ? gq.z : gq.w;
            num[0] += g;
            float p = b;
            den[1] += p; num[1] = fmaf(p, g, num[1]);
            #pragma unroll
            for (int k = 2; k < KT; ++k) {
                p *= b;                       // b^k
                den[k] += p;
                num[k]  = fmaf(p, g, num[k]);
            }
        }

        // butterfly within the 16-lane group (xor 1,2,4,8 keeps c fixed)
        #pragma unroll
        for (int off = 1; off <= 8; off <<= 1) {
            num[0] += __shfl_xor(num[0], off);
            #pragma unroll
            for (int k = 1; k < KT; ++k) {
                den[k] += __shfl_xor(den[k], off);
                num[k] += __shfl_xor(num[k], off);
            }
        }

        // lane l == k writes power k (all lanes hold identical sums)
        float* pp = partial + blockIdx.x * NCOEF;
        const int cg = cg0 + c;
        #pragma unroll
        for (int k = 0; k < 16; ++k) {
            if (l == k) {
                pp[k * 32 + cg]       = (k == 0) ? (float)T1 : den[k];
                pp[544 + k * 32 + cg] = num[k];
            }
        }
        if (l == 0) {
            pp[16 * 32 + cg]       = den[16];
            pp[544 + 16 * 32 + cg] = num[16];
        }
    }
}

// ---------------------------------------------------------------------------
// K2: 144 blocks x 256 (verbatim from round 9). Reduce partial[36][1088] ->
// cfl[c][44] (1/k! folded, transposed); Horner y = num(a)/den(a) from v1;
// out-projection + residual.
// ---------------------------------------------------------------------------
__global__ __launch_bounds__(256) void k_eval(
    const float* __restrict__ x,
    const float* __restrict__ kw, const float* __restrict__ kb,
    const float* __restrict__ v1, const float* __restrict__ partial,
    float* __restrict__ out)
{
    __shared__ float kwt[CHALF][68];            // [c][co]
    __shared__ __align__(16) float cfl[CHALF][CSTRIDE];
    __shared__ float ys[T2][36];                // [pos][c]
    __shared__ float kbs[CIN];

    const int tid = threadIdx.x;
    const int n0  = blockIdx.x * T2;

    for (int idx = tid; idx < CIN * CHALF; idx += 256) {
        int co = idx >> 5, c = idx & 31;
        kwt[c][co] = kw[idx];                   // kw row-major [co=64][c=32]
    }
    if (tid < CIN) kbs[tid] = kb[tid];

    // ---- reduce 36 partial rows (deterministic order), fold 1/k! -----------
    for (int col = tid; col < NCOEF / 4; col += 256) {
        float4 v = make_float4(0.f, 0.f, 0.f, 0.f);
        #pragma unroll 6
        for (int s = 0; s < NB1; ++s) {
            float4 p = *(const float4*)&partial[s * NCOEF + col * 4];
            v.x += p.x; v.y += p.y; v.z += p.z; v.w += p.w;
        }
        #pragma unroll
        for (int i = 0; i < 4; ++i) {
            int   e  = col * 4 + i;
            int   dn = (e >= 544) ? 1 : 0;
            int   k  = (e - dn * 544) >> 5;
            int   c  = e & 31;
            float vv = (i==0) ? v.x : (i==1) ? v.y : (i==2) ? v.z : v.w;
            cfl[c][dn * 20 + k] = vv * INVF_C[k];
        }
    }
    __syncthreads();

    // ---- Horner: thread = (c = tid>>3, pp = tid&7), 2 positions ------------
    {
        const int c  = tid >> 3;
        const int pp = tid & 7;
        float dc[20], nc[20];
        #pragma unroll
        for (int qq = 0; qq < 5; ++qq) {
            *(float4*)&dc[qq * 4] = *(const float4*)&cfl[c][qq * 4];
            *(float4*)&nc[qq * 4] = *(const float4*)&cfl[c][20 + qq * 4];
        }
        float2 a2 = *(const float2*)&v1[c * N + n0 + pp * 2];
        #pragma unroll
        for (int e = 0; e < 2; ++e) {
            float a   = e ? a2.y : a2.x;
            float den = dc[KT - 1], num = nc[KT - 1];
            #pragma unroll
            for (int k = KT - 2; k >= 0; --k) {
                den = fmaf(den, a, dc[k]);
                num = fmaf(num, a, nc[k]);
            }
            ys[pp * 2 + e][c] = num / den;
        }
    }
    __syncthreads();

    // ---- out-projection + residual: thread = (pos = tid&15, coq = tid>>4) --
    {
        const int pos = tid & 15;
        const int coq = tid >> 4;               // 0..15 -> co = coq*4 + i
        float yv[CHALF];
        #pragma unroll
        for (int qq = 0; qq < 8; ++qq)
            *(float4*)&yv[qq * 4] = *(const float4*)&ys[pos][qq * 4];

        float acc[4] = {0.f, 0.f, 0.f, 0.f};
        #pragma unroll
        for (int c = 0; c < CHALF; ++c) {
            float4 wv = *(const float4*)&kwt[c][coq * 4];
            acc[0] = fmaf(wv.x, yv[c], acc[0]);
            acc[1] = fmaf(wv.y, yv[c], acc[1]);
            acc[2] = fmaf(wv.z, yv[c], acc[2]);
            acc[3] = fmaf(wv.w, yv[c], acc[3]);
        }
        #pragma unroll
        for (int i = 0; i < 4; ++i) {
            int off = (coq * 4 + i) * N + n0 + pos;
            out[off] = x[off] + acc[i] + kbs[coq * 4 + i];
        }
    }
}

// ---------------------------------------------------------------------------
extern "C" void kernel_launch(void* const* d_in, const int* in_sizes, int n_in,
                              void* d_out, int out_size, void* d_ws, size_t ws_size,
                              hipStream_t stream)
{
    const float* x  = (const float*)d_in[0];
    const float* tw = (const float*)d_in[1];
    const float* tb = (const float*)d_in[2];
    const float* pw = (const float*)d_in[3];
    const float* pb = (const float*)d_in[4];
    const float* gw = (const float*)d_in[5];
    const float* gb = (const float*)d_in[6];
    const float* kw = (const float*)d_in[7];
    const float* kb = (const float*)d_in[8];
    float* out = (float*)d_out;

    // workspace (floats): v1 @0 (73728), partial[36][1088] @73728
    float* ws      = (float*)d_ws;
    float* v1      = ws;
    float* partial = ws + 73728;

    k_pm<<<dim3(NB1, 8), dim3(64), 0, stream>>>(
        x, tw, tb, pw, pb, gw, gb, v1, partial);

    k_eval<<<dim3(NB2), dim3(256), 0, stream>>>(
        x, kw, kb, v1, partial, out);
}